// Round 5
// baseline (678.961 us; speedup 1.0000x reference)
//
#include <hip/hip_runtime.h>
#include <hip/hip_bf16.h>
#include <cstdint>

// Problem constants
#define B_     2
#define N_     100000
#define C_     256
#define H_     8
#define D_     64
#define S_     64
#define INNER_ 512

#define TILE_T 64
#define NTILES ((N_ + TILE_T - 1) / TILE_T)   // 1563
#define PBLK   32                             // grid = 32*8*2 = 512 blocks of 512 thr (2/CU)

// Workspace layout (bytes)
#define WEFFT_OFF 0                           // bf16 [H][S][C]   = 262144  (pre-scaled log2e/temp)
#define WFXT_OFF  262144                      // bf16 [H][D][C]   = 262144
#define BIASE_OFF 524288                      // f32  [H][S]      = 2048    (pre-scaled)
// big path (atomic-free): per-block slabs
#define SLAB_OFF  526336                      // f32 [B*H][PBLK][4096]
#define NSLAB_OFF (SLAB_OFF + B_*H_*PBLK*4096*4)
#define WS_BIG_END (NSLAB_OFF + B_*H_*PBLK*64*4)   // ~9.05 MB
// small (fallback) path:
#define ACC_OFF   526336
#define NRM_OFF   (ACC_OFF + B_*H_*S_*D_*4)
#define WS_SMALL_END (NRM_OFF + B_*H_*S_*4)

// xs row stride in shorts: 272 -> row stride 136 dwords === 8 (mod 32)
// A-read banks = 8*(l&3)+4*q -> 4-way (1.58x) instead of 264's 8-way (2.94x)
#define XSP 272

typedef __attribute__((ext_vector_type(8))) short short8;
typedef __attribute__((ext_vector_type(4))) float f32x4;

__device__ inline short f2bf(float f) {
    __hip_bfloat16 h = __float2bfloat16(f);
    short s; __builtin_memcpy(&s, &h, 2); return s;
}
__device__ inline uint32_t pk2(float a, float b) {
    __hip_bfloat162 h = __float22bfloat162_rn(float2{a, b});
    uint32_t u; __builtin_memcpy(&u, &h, 4); return u;
}

// ---------------------------------------------------------------------------
// prep: wave-per-(h,k). Lane = s (or d) -> W_slice coalesced, W_x scalar.
// ---------------------------------------------------------------------------
__global__ void prep_kernel(const float* __restrict__ W_x,
                            const float* __restrict__ b_x,
                            const float* __restrict__ W_fx,
                            const float* __restrict__ W_slice,
                            const float* __restrict__ b_slice,
                            const float* __restrict__ temperature,
                            uint8_t* __restrict__ wsb) {
    int wid  = (blockIdx.x * 256 + threadIdx.x) >> 6;
    int lane = threadIdx.x & 63;
    if (wid < H_ * C_) {                       // W_eff (scaled)
        int h = wid >> 8, k = wid & 255;
        float t = temperature[h]; t = fminf(fmaxf(t, 0.1f), 5.0f);
        float sc = 1.44269504088896f / t;
        const float* wx = W_x + k * INNER_ + h * 64;   // wave-uniform -> s_load
        float a = 0.f;
        #pragma unroll 8
        for (int d = 0; d < D_; ++d)
            a = fmaf(wx[d], W_slice[d * 64 + lane], a);
        ((short*)(wsb + WEFFT_OFF))[(h * 64 + lane) * 256 + k] = f2bf(a * sc);
    } else if (wid < 2 * H_ * C_) {            // W_fx repack
        int j = wid - H_ * C_;
        int h = j >> 8, k = j & 255;
        ((short*)(wsb + WFXT_OFF))[(h * 64 + lane) * 256 + k] =
            f2bf(W_fx[k * INNER_ + h * 64 + lane]);
    } else if (wid < 2 * H_ * C_ + H_) {       // bias (scaled)
        int h = wid - 2 * H_ * C_;
        float t = temperature[h]; t = fminf(fmaxf(t, 0.1f), 5.0f);
        float sc = 1.44269504088896f / t;
        float a = 0.f;
        #pragma unroll 8
        for (int d = 0; d < D_; ++d)
            a = fmaf(b_x[h * 64 + d], W_slice[d * 64 + lane], a);
        ((float*)(wsb + BIASE_OFF))[h * 64 + lane] = (a + b_slice[lane]) * sc;
    }
}

// ---------------------------------------------------------------------------
// main v5: 512-thr / 8 waves. Wave role: g = wv&1 (0 logits / 1 fx),
//   nh = (wv>>1)&1 (32-n half, breg[2][8] = 64 VGPR), th = wv>>2 (32-token half).
//   A-frag reuse R=2 -> main LDS reads halved vs v4. 3 barriers/tile:
//   pack -> B2 -> MFMA + exp/publish + fsl-write -> B3 -> combine + wsl-write
//   -> B4 -> agg MFMA. No overlay (xs/wsl/fsl separate) so no B1.
// ---------------------------------------------------------------------------
template<bool SLAB>
__global__ __launch_bounds__(512, 4) void main_kernel(
        const float* __restrict__ x,
        const float* __restrict__ b_fx,
        const uint8_t* __restrict__ wsb,
        float* __restrict__ accg,
        float* __restrict__ nrmg) {
    __shared__ short xs[TILE_T * XSP];        // 34816 B
    __shared__ short wsl[S_ * 72];            // 9216 B
    __shared__ short fsl[D_ * 72];            // 9216 B
    __shared__ float smB[TILE_T * 2];         // [tok][nh] partial sumexp (512 B)

    const int tid = threadIdx.x;
    const int bid = blockIdx.x;
    // XCD swizzle: 8 h-siblings of each (p,b) share bid%8 -> same XCD
    const int cc = bid & 7;
    const int h  = (bid >> 3) & 7;
    const int pb = (bid >> 6) * 8 + cc;       // [0,64)
    const int p  = pb & 31;
    const int b  = pb >> 5;

    const int lane = tid & 63, wv = tid >> 6;
    const int l = lane & 15, q = lane >> 4;
    const int g  = wv & 1;                    // 0: logits (s), 1: fx (d)
    const int nh = (wv >> 1) & 1;             // 32-wide n half
    const int th = wv >> 2;                   // 32-token half

    // persistent B-frags: 2 x 16-n strips (64 VGPRs)
    const short* wT = (const short*)(wsb + (g ? WFXT_OFF : WEFFT_OFF)) + h * (64 * 256);
    short8 breg[2][8];
    #pragma unroll
    for (int nt = 0; nt < 2; ++nt)
        #pragma unroll
        for (int k = 0; k < 8; ++k)
            breg[nt][k] = *(const short8*)(wT + (nh * 32 + nt * 16 + l) * 256 + k * 32 + q * 8);

    float bias_n[2];
    #pragma unroll
    for (int nt = 0; nt < 2; ++nt) {
        int n = nh * 32 + nt * 16 + l;
        bias_n[nt] = g ? b_fx[h * 64 + n] : ((const float*)(wsb + BIASE_OFF))[h * 64 + n];
    }

    const float* xb = x + (size_t)b * ((size_t)N_ * C_);
    f32x4 accO[2] = {};                       // agg out [16 s][32 d], persistent
    float nrmacc[2] = {0.f, 0.f};

    // prologue: prefetch rows 0-31 of first tile (4 float4 = 16 VGPR)
    float4 xv[4];
    {
        const int col = lane * 4;
        #pragma unroll
        for (int j = 0; j < 4; ++j) {
            int gt = p * TILE_T + wv + 8 * j;
            xv[j] = (gt < N_) ? *(const float4*)(xb + (size_t)gt * C_ + col)
                              : float4{0.f, 0.f, 0.f, 0.f};
        }
    }

    #pragma unroll 1
    for (int tile = p; tile < NTILES; tile += PBLK) {
        const int t0 = tile * TILE_T;
        // ---- pack: issue direct loads (rows 32-63), write prefetched rows,
        //      then write direct rows (load latency hidden under reg writes)
        {
            const int col = lane * 4;
            float4 dv4[4];
            #pragma unroll
            for (int j = 0; j < 4; ++j) {
                int gt = t0 + wv + 8 * (j + 4);
                dv4[j] = (gt < N_) ? *(const float4*)(xb + (size_t)gt * C_ + col)
                                   : float4{0.f, 0.f, 0.f, 0.f};
            }
            #pragma unroll
            for (int j = 0; j < 4; ++j) {
                int row = wv + 8 * j;
                uint2 pk = { pk2(xv[j].x, xv[j].y), pk2(xv[j].z, xv[j].w) };
                *(uint2*)(xs + row * XSP + col) = pk;
            }
            #pragma unroll
            for (int j = 0; j < 4; ++j) {
                int row = wv + 8 * (j + 4);
                uint2 pk = { pk2(dv4[j].x, dv4[j].y), pk2(dv4[j].z, dv4[j].w) };
                *(uint2*)(xs + row * XSP + col) = pk;
            }
        }
        __syncthreads();                      // B2: xs ready

        // ---- prefetch next tile rows 0-31 (hides under compute)
        {
            int nxt = tile + PBLK;
            if (nxt < NTILES) {
                const int col = lane * 4;
                #pragma unroll
                for (int j = 0; j < 4; ++j) {
                    int gt = nxt * TILE_T + wv + 8 * j;
                    xv[j] = (gt < N_) ? *(const float4*)(xb + (size_t)gt * C_ + col)
                                      : float4{0.f, 0.f, 0.f, 0.f};
                }
            }
        }

        // ---- main MFMA GEMM: 2 m-strips x 2 n-strips, A-frag reused 2x
        f32x4 acc[2][2] = {};
        #pragma unroll
        for (int k = 0; k < 8; ++k) {
            short8 a0 = *(const short8*)(xs + (th * 32 + l) * XSP + k * 32 + q * 8);
            short8 a1 = *(const short8*)(xs + (th * 32 + 16 + l) * XSP + k * 32 + q * 8);
            #pragma unroll
            for (int nt = 0; nt < 2; ++nt) {
                acc[0][nt] = __builtin_amdgcn_mfma_f32_16x16x32_bf16(a0, breg[nt][k], acc[0][nt], 0, 0, 0);
                acc[1][nt] = __builtin_amdgcn_mfma_f32_16x16x32_bf16(a1, breg[nt][k], acc[1][nt], 0, 0, 0);
            }
        }

        if (g == 0) {
            // logits pre-scaled to log2 domain: exp2, 16-lane partial sums,
            // publish per-(tok, nh)
            #pragma unroll
            for (int m = 0; m < 2; ++m)
                #pragma unroll
                for (int r = 0; r < 4; ++r) {
                    float e0 = __builtin_amdgcn_exp2f(acc[m][0][r] + bias_n[0]);
                    float e1 = __builtin_amdgcn_exp2f(acc[m][1][r] + bias_n[1]);
                    acc[m][0][r] = e0; acc[m][1][r] = e1;
                    float sv = e0 + e1;
                    sv += __shfl_xor(sv, 1, 64);
                    sv += __shfl_xor(sv, 2, 64);
                    sv += __shfl_xor(sv, 4, 64);
                    sv += __shfl_xor(sv, 8, 64);
                    if (l == 0)
                        smB[(th * 32 + m * 16 + q * 4 + r) * 2 + nh] = sv;
                }
        } else {
            // fx: add bias, write fsl now (no cross-wave dependency)
            #pragma unroll
            for (int m = 0; m < 2; ++m)
                #pragma unroll
                for (int nt = 0; nt < 2; ++nt) {
                    int dd = nh * 32 + nt * 16 + l, tt = th * 32 + m * 16 + q * 4;
                    uint2 pk = { pk2(acc[m][nt][0] + bias_n[nt], acc[m][nt][1] + bias_n[nt]),
                                 pk2(acc[m][nt][2] + bias_n[nt], acc[m][nt][3] + bias_n[nt]) };
                    *(uint2*)(fsl + dd * 72 + tt) = pk;
                }
        }
        __syncthreads();                      // B3: smB + fsl ready

        if (g == 0) {
            // combine nh-halves, normalize, write w -> wsl
            #pragma unroll
            for (int m = 0; m < 2; ++m) {
                #pragma unroll
                for (int r = 0; r < 4; ++r) {
                    int tok = th * 32 + m * 16 + q * 4 + r;
                    float2 s2 = *(const float2*)(smB + tok * 2);
                    float S = s2.x + s2.y;
                    float f = __builtin_amdgcn_rcpf(S);
                    if (t0 + tok >= N_) f = 0.f;
                    float w0 = acc[m][0][r] * f, w1 = acc[m][1][r] * f;
                    nrmacc[0] += w0; nrmacc[1] += w1;
                    acc[m][0][r] = w0; acc[m][1][r] = w1;
                }
                #pragma unroll
                for (int nt = 0; nt < 2; ++nt) {
                    int ss = nh * 32 + nt * 16 + l, tt = th * 32 + m * 16 + q * 4;
                    uint2 pk = { pk2(acc[m][nt][0], acc[m][nt][1]),
                                 pk2(acc[m][nt][2], acc[m][nt][3]) };
                    *(uint2*)(wsl + ss * 72 + tt) = pk;
                }
            }
        }
        __syncthreads();                      // B4: wsl ready

        // ---- aggregation MFMA: wave = (s-strip sv_, d-half dv)
        {
            const int sv_ = wv & 3, dv = wv >> 2;
            #pragma unroll
            for (int kk = 0; kk < 2; ++kk) {
                short8 aw = *(const short8*)(wsl + (sv_ * 16 + l) * 72 + kk * 32 + q * 8);
                #pragma unroll
                for (int nt = 0; nt < 2; ++nt) {
                    short8 bf = *(const short8*)(fsl + (dv * 32 + nt * 16 + l) * 72 + kk * 32 + q * 8);
                    accO[nt] = __builtin_amdgcn_mfma_f32_16x16x32_bf16(aw, bf, accO[nt], 0, 0, 0);
                }
            }
        }
    }

    // ---- flush accO: rows s = sv_*16+q*4+r, cols d = dv*32+nt*16+l
    {
        const int sv_ = wv & 3, dv = wv >> 2;
        if (SLAB) {
            float* sp = accg + ((size_t)(b * H_ + h) * PBLK + p) * 4096;
            #pragma unroll
            for (int nt = 0; nt < 2; ++nt)
                #pragma unroll
                for (int r = 0; r < 4; ++r)
                    sp[(sv_ * 16 + q * 4 + r) * 64 + dv * 32 + nt * 16 + l] = accO[nt][r];
        } else {
            float* ag = accg + (size_t)((b * H_ + h) * 64) * 64;
            #pragma unroll
            for (int nt = 0; nt < 2; ++nt)
                #pragma unroll
                for (int r = 0; r < 4; ++r)
                    atomicAdd(ag + (sv_ * 16 + q * 4 + r) * 64 + dv * 32 + nt * 16 + l, accO[nt][r]);
        }
    }

    // ---- nrm: combine th-halves via smB, then flush
    __syncthreads();
    if (g == 0) {
        #pragma unroll
        for (int nt = 0; nt < 2; ++nt) {
            float v = nrmacc[nt];
            v += __shfl_xor(v, 16, 64);
            v += __shfl_xor(v, 32, 64);
            if (lane < 16)
                smB[(nh * 32 + nt * 16 + lane) * 2 + th] = v;
        }
    }
    __syncthreads();
    if (g == 0 && th == 0 && lane < 16) {
        #pragma unroll
        for (int nt = 0; nt < 2; ++nt) {
            int s = nh * 32 + nt * 16 + lane;
            float v = smB[s * 2] + smB[s * 2 + 1];
            if (SLAB)
                nrmg[((b * H_ + h) * PBLK + p) * 64 + s] = v;
            else
                atomicAdd(nrmg + (b * H_ + h) * 64 + s, v);
        }
    }
}

// ---------------------------------------------------------------------------
__global__ void finalize_big(const float* __restrict__ slab,
                             const float* __restrict__ nslab,
                             float* __restrict__ out) {
    int idx = blockIdx.x * 256 + threadIdx.x;  // 65536
    int bh = idx >> 12, sd = idx & 4095, s = sd >> 6;
    const float* sp = slab  + (size_t)bh * PBLK * 4096 + sd;
    const float* np = nslab + bh * PBLK * 64 + s;
    float acc = 0.f, nn = 0.f;
    #pragma unroll 8
    for (int p = 0; p < PBLK; ++p) { acc += sp[p * 4096]; nn += np[p * 64]; }
    out[idx] = acc / (nn + 1e-5f);
}

__global__ void finalize_small(const uint8_t* __restrict__ wsb, float* __restrict__ out) {
    int idx = blockIdx.x * 256 + threadIdx.x;
    float a = ((const float*)(wsb + ACC_OFF))[idx];
    float n = ((const float*)(wsb + NRM_OFF))[idx / D_];
    out[idx] = a / (n + 1e-5f);
}

// ---------------------------------------------------------------------------
extern "C" void kernel_launch(void* const* d_in, const int* in_sizes, int n_in,
                              void* d_out, int out_size, void* d_ws, size_t ws_size,
                              hipStream_t stream) {
    const float* x           = (const float*)d_in[0];
    const float* W_x         = (const float*)d_in[1];
    const float* b_x         = (const float*)d_in[2];
    const float* W_fx        = (const float*)d_in[3];
    const float* b_fx        = (const float*)d_in[4];
    const float* W_slice     = (const float*)d_in[5];
    const float* b_slice     = (const float*)d_in[6];
    const float* temperature = (const float*)d_in[7];
    float* out = (float*)d_out;
    uint8_t* wsb = (uint8_t*)d_ws;

    int prep_waves = 2 * H_ * C_ + H_;                 // 4104
    prep_kernel<<<dim3((prep_waves + 3) / 4), dim3(256), 0, stream>>>(
        W_x, b_x, W_fx, W_slice, b_slice, temperature, wsb);

    if (ws_size >= (size_t)WS_BIG_END) {
        main_kernel<true><<<dim3(PBLK * H_ * B_), dim3(512), 0, stream>>>(
            x, b_fx, wsb, (float*)(wsb + SLAB_OFF), (float*)(wsb + NSLAB_OFF));
        finalize_big<<<dim3(256), dim3(256), 0, stream>>>(
            (const float*)(wsb + SLAB_OFF), (const float*)(wsb + NSLAB_OFF), out);
    } else {
        hipMemsetAsync(wsb + ACC_OFF, 0, (B_ * H_ * S_ * D_ + B_ * H_ * S_) * 4, stream);
        main_kernel<false><<<dim3(PBLK * H_ * B_), dim3(512), 0, stream>>>(
            x, b_fx, wsb, (float*)(wsb + ACC_OFF), (float*)(wsb + NRM_OFF));
        finalize_small<<<dim3(256), dim3(256), 0, stream>>>(wsb, out);
    }
}